// Round 2
// baseline (1612.720 us; speedup 1.0000x reference)
//
#include <hip/hip_runtime.h>

#define N_USERS 100000
#define N_ITEMS 50000
#define N_NODES 150000
#define NEDGES  4000000
#define EMB     64
#define BATCH   16384
#define BSHIFT  6                       // 64 rows per bucket
#define NB      ((N_NODES + 63) >> 6)   // 2344 buckets

// ---------------- CSR build ----------------

__global__ void k_zero(int* __restrict__ counts, int* __restrict__ rcursor,
                       int* __restrict__ bcursor) {
    int i = blockIdx.x * blockDim.x + threadIdx.x;
    if (i < N_NODES) { counts[i] = 0; rcursor[i] = 0; }
    if (i < NB) bcursor[i] = 0;
}

__global__ void k_hist(const int* __restrict__ erow, int* __restrict__ counts) {
    int e = blockIdx.x * blockDim.x + threadIdx.x;
    if (e < NEDGES) atomicAdd(&counts[erow[e]], 1);
}

// single-block exclusive scan of counts -> rowptr (N_NODES+1 entries)
__global__ __launch_bounds__(1024) void k_scan(const int* __restrict__ counts,
                                               int* __restrict__ rowptr) {
    __shared__ int lds[1024];
    const int t = threadIdx.x;
    const int CH = (N_NODES + 1023) / 1024;  // 147
    int beg = t * CH;
    int end = beg + CH; if (end > N_NODES) end = N_NODES;
    int s = 0;
    for (int i = beg; i < end; ++i) s += counts[i];
    lds[t] = s;
    __syncthreads();
    for (int off = 1; off < 1024; off <<= 1) {
        int u = (t >= off) ? lds[t - off] : 0;
        __syncthreads();
        lds[t] += u;
        __syncthreads();
    }
    int run = lds[t] - s;  // exclusive prefix of this chunk
    for (int i = beg; i < end; ++i) { rowptr[i] = run; run += counts[i]; }
    if (t == 1023) rowptr[N_NODES] = lds[1023];
}

__global__ void k_dinv(const int* __restrict__ counts, float* __restrict__ dinv) {
    int i = blockIdx.x * blockDim.x + threadIdx.x;
    if (i < N_NODES) dinv[i] = 1.0f / (sqrtf((float)counts[i]) + 1e-6f);
}

// phase C: bin edges into 64-row buckets; pack (row_local<<18 | col) in u32.
// Per-bucket append heads cluster writes -> L2 write-combining, ~1x traffic.
__global__ void k_bucket(const int* __restrict__ erow, const int* __restrict__ ecol,
                         const int* __restrict__ rowptr, int* __restrict__ bcursor,
                         unsigned int* __restrict__ tmp) {
    int e = blockIdx.x * blockDim.x + threadIdx.x;
    if (e >= NEDGES) return;
    int row = erow[e];
    int col = ecol[e];
    int b = row >> BSHIFT;
    int pos = atomicAdd(&bcursor[b], 1);
    tmp[rowptr[b << BSHIFT] + pos] =
        ((unsigned int)(row & 63) << 18) | (unsigned int)col;
}

// phase D: place each bucket's edges into exact CSR slots (col only, 4B).
// Random writes confined to ~7KB per-bucket windows (L2-resident).
__global__ void k_place(const unsigned int* __restrict__ tmp,
                        const int* __restrict__ rowptr, int* __restrict__ rcursor,
                        int* __restrict__ csrc) {
    int b = blockIdx.x;
    int rbeg = b << BSHIFT;
    int rend = rbeg + 64; if (rend > N_NODES) rend = N_NODES;
    int base = rowptr[rbeg];
    int stop = rowptr[rend];
    for (int i = base + threadIdx.x; i < stop; i += blockDim.x) {
        unsigned int pk = tmp[i];
        int row = rbeg + (int)(pk >> 18);
        int col = (int)(pk & 0x3FFFFu);
        int slot = rowptr[row] + atomicAdd(&rcursor[row], 1);
        csrc[slot] = col;
    }
}

// ---------------- SpMM: 16-lane group per row, float4 per lane, unroll x2 ----

__global__ void k_spmm(const float* __restrict__ Ein, float* __restrict__ Eout,
                       const int* __restrict__ rowptr, const int* __restrict__ cols,
                       const float* __restrict__ dinv) {
    int g    = (blockIdx.x * blockDim.x + threadIdx.x) >> 4;
    int lane = threadIdx.x & 15;
    if (g >= N_NODES) return;
    int beg = rowptr[g], end = rowptr[g + 1];
    float4 a0 = make_float4(0.f, 0.f, 0.f, 0.f);
    float4 a1 = make_float4(0.f, 0.f, 0.f, 0.f);
    int j = beg;
    for (; j + 2 <= end; j += 2) {
        int c0 = cols[j], c1 = cols[j + 1];
        float d0 = dinv[c0], d1 = dinv[c1];
        float4 x0 = ((const float4*)(Ein + (size_t)c0 * EMB))[lane];
        float4 x1 = ((const float4*)(Ein + (size_t)c1 * EMB))[lane];
        a0.x = fmaf(d0, x0.x, a0.x); a0.y = fmaf(d0, x0.y, a0.y);
        a0.z = fmaf(d0, x0.z, a0.z); a0.w = fmaf(d0, x0.w, a0.w);
        a1.x = fmaf(d1, x1.x, a1.x); a1.y = fmaf(d1, x1.y, a1.y);
        a1.z = fmaf(d1, x1.z, a1.z); a1.w = fmaf(d1, x1.w, a1.w);
    }
    if (j < end) {
        int c0 = cols[j];
        float d0 = dinv[c0];
        float4 x0 = ((const float4*)(Ein + (size_t)c0 * EMB))[lane];
        a0.x = fmaf(d0, x0.x, a0.x); a0.y = fmaf(d0, x0.y, a0.y);
        a0.z = fmaf(d0, x0.z, a0.z); a0.w = fmaf(d0, x0.w, a0.w);
    }
    float dr = dinv[g];
    float4 o;
    o.x = dr * (a0.x + a1.x); o.y = dr * (a0.y + a1.y);
    o.z = dr * (a0.z + a1.z); o.w = dr * (a0.w + a1.w);
    ((float4*)(Eout + (size_t)g * EMB))[lane] = o;
}

// ---------------- batch-row gather: init and accumulate ----------------

__global__ void k_gather_init(const float* __restrict__ E0, const int* __restrict__ ub,
                              const int* __restrict__ ib, float* __restrict__ U,
                              float* __restrict__ I) {
    int g    = (blockIdx.x * blockDim.x + threadIdx.x) >> 4;
    int lane = threadIdx.x & 15;
    if (g >= 2 * BATCH) return;
    if (g < BATCH) {
        int r = ub[g];
        ((float4*)(U + (size_t)g * EMB))[lane] =
            ((const float4*)(E0 + (size_t)r * EMB))[lane];
    } else {
        int b = g - BATCH;
        int r = N_USERS + ib[b];
        ((float4*)(I + (size_t)b * EMB))[lane] =
            ((const float4*)(E0 + (size_t)r * EMB))[lane];
    }
}

__global__ void k_gather_acc(const float* __restrict__ E, const int* __restrict__ ub,
                             const int* __restrict__ ib, float* __restrict__ U,
                             float* __restrict__ I) {
    int g    = (blockIdx.x * blockDim.x + threadIdx.x) >> 4;
    int lane = threadIdx.x & 15;
    if (g >= 2 * BATCH) return;
    if (g < BATCH) {
        int r = ub[g];
        float4 x = ((const float4*)(E + (size_t)r * EMB))[lane];
        float4* dst = (float4*)(U + (size_t)g * EMB) + lane;
        float4 a = *dst;
        a.x += x.x; a.y += x.y; a.z += x.z; a.w += x.w;
        *dst = a;
    } else {
        int b = g - BATCH;
        int r = N_USERS + ib[b];
        float4 x = ((const float4*)(E + (size_t)r * EMB))[lane];
        float4* dst = (float4*)(I + (size_t)b * EMB) + lane;
        float4 a = *dst;
        a.x += x.x; a.y += x.y; a.z += x.z; a.w += x.w;
        *dst = a;
    }
}

// ---------------- final dot ----------------

__global__ void k_dot(const float* __restrict__ U, const float* __restrict__ I,
                      float* __restrict__ out) {
    int g    = (blockIdx.x * blockDim.x + threadIdx.x) >> 4;
    int lane = threadIdx.x & 15;
    if (g >= BATCH) return;
    float4 a = ((const float4*)(U + (size_t)g * EMB))[lane];
    float4 b = ((const float4*)(I + (size_t)g * EMB))[lane];
    float p = a.x * b.x + a.y * b.y + a.z * b.z + a.w * b.w;
    for (int m = 1; m < 16; m <<= 1) p += __shfl_xor(p, m, 64);
    if (lane == 0) out[g] = p * (1.0f / 16.0f);  // 1/(K+1)^2
}

// ---------------- launch ----------------

static inline char* align16(char* p) {
    return (char*)(((uintptr_t)p + 15) & ~(uintptr_t)15);
}

extern "C" void kernel_launch(void* const* d_in, const int* in_sizes, int n_in,
                              void* d_out, int out_size, void* d_ws, size_t ws_size,
                              hipStream_t stream) {
    const float* E0   = (const float*)d_in[0];
    const int*   erow = (const int*)d_in[2];
    const int*   ecol = (const int*)d_in[3];
    const int*   ub   = (const int*)d_in[4];
    const int*   ib   = (const int*)d_in[5];
    float* pred = (float*)d_out;

    char* p = (char*)d_ws;
    float* A       = (float*)p; p = align16(p + (size_t)N_NODES * EMB * 4);
    float* B       = (float*)p; p = align16(p + (size_t)N_NODES * EMB * 4);
    float* U       = (float*)p; p = align16(p + (size_t)BATCH * EMB * 4);
    float* I       = (float*)p; p = align16(p + (size_t)BATCH * EMB * 4);
    int*   counts  = (int*)p;   p = align16(p + (size_t)N_NODES * 4);
    int*   rcursor = (int*)p;   p = align16(p + (size_t)N_NODES * 4);
    int*   bcursor = (int*)p;   p = align16(p + (size_t)NB * 4);
    int*   rowptr  = (int*)p;   p = align16(p + (size_t)(N_NODES + 1) * 4);
    float* dinv    = (float*)p; p = align16(p + (size_t)N_NODES * 4);
    int*   csrc    = (int*)p;   p = align16(p + (size_t)NEDGES * 4);
    unsigned int* tmp = (unsigned int*)B;  // phase C/D staging; dead before hop 2

    const int BS = 256;
    k_zero<<<(N_NODES + BS - 1) / BS, BS, 0, stream>>>(counts, rcursor, bcursor);
    k_hist<<<(NEDGES + BS - 1) / BS, BS, 0, stream>>>(erow, counts);
    k_scan<<<1, 1024, 0, stream>>>(counts, rowptr);
    k_dinv<<<(N_NODES + BS - 1) / BS, BS, 0, stream>>>(counts, dinv);
    k_bucket<<<(NEDGES + BS - 1) / BS, BS, 0, stream>>>(erow, ecol, rowptr, bcursor, tmp);
    k_place<<<NB, BS, 0, stream>>>(tmp, rowptr, rcursor, csrc);

    k_gather_init<<<(2 * BATCH * 16 + BS - 1) / BS, BS, 0, stream>>>(E0, ub, ib, U, I);

    const int spmm_grid = (N_NODES * 16 + BS - 1) / BS;
    const int acc_grid  = (2 * BATCH * 16 + BS - 1) / BS;

    // hop 1: E0 -> A
    k_spmm<<<spmm_grid, BS, 0, stream>>>(E0, A, rowptr, csrc, dinv);
    k_gather_acc<<<acc_grid, BS, 0, stream>>>(A, ub, ib, U, I);
    // hop 2: A -> B
    k_spmm<<<spmm_grid, BS, 0, stream>>>(A, B, rowptr, csrc, dinv);
    k_gather_acc<<<acc_grid, BS, 0, stream>>>(B, ub, ib, U, I);
    // hop 3: B -> A
    k_spmm<<<spmm_grid, BS, 0, stream>>>(B, A, rowptr, csrc, dinv);
    k_gather_acc<<<acc_grid, BS, 0, stream>>>(A, ub, ib, U, I);

    // readout
    k_dot<<<(BATCH * 16 + BS - 1) / BS, BS, 0, stream>>>(U, I, pred);
}

// Round 3
// 653.709 us; speedup vs baseline: 2.4670x; 2.4670x over previous
//
#include <hip/hip_runtime.h>

#define N_USERS 100000
#define N_ITEMS 50000
#define N_NODES 150000
#define NEDGES  4000000
#define EMB     64
#define BATCH   16384

#define RSHIFT  9
#define RPB     512                          // rows per bucket
#define NBKT    ((N_NODES + RPB - 1) / RPB)  // 293
#define BCAP    24576                        // max edges/bucket (mean 20.5K items, +28 sigma)

#define PC_BS   1024
#define PC_CH   16384
#define PC_NWG  ((NEDGES + PC_CH - 1) / PC_CH)  // 245

// ---------------- helpers ----------------

__device__ __forceinline__ unsigned short f2b(float f) {  // fp32 -> bf16 RNE
    unsigned u = __float_as_uint(f);
    return (unsigned short)((u + 0x7FFFu + ((u >> 16) & 1u)) >> 16);
}
__device__ __forceinline__ float b2f_lo(unsigned v) { return __uint_as_float(v << 16); }
__device__ __forceinline__ float b2f_hi(unsigned v) { return __uint_as_float(v & 0xFFFF0000u); }

// ---------------- CSR build ----------------

__global__ void k_zero(int* __restrict__ bcursor) {
    int i = blockIdx.x * blockDim.x + threadIdx.x;
    if (i < NBKT) bcursor[i] = 0;
}

// LDS-staged bucket partition: count in LDS, one global atomic per (wg,bucket),
// then scatter packed (row_local<<18 | col) into fixed-cap bucket regions.
__global__ __launch_bounds__(PC_BS) void k_partC(const int* __restrict__ erow,
                                                 const int* __restrict__ ecol,
                                                 int* __restrict__ bcursor,
                                                 unsigned* __restrict__ tmp) {
    __shared__ int cnt[NBKT];
    __shared__ int base_[NBKT];
    const int t = threadIdx.x;
    for (int i = t; i < NBKT; i += PC_BS) cnt[i] = 0;
    __syncthreads();
    const int e0 = blockIdx.x * PC_CH;
#pragma unroll
    for (int k = 0; k < PC_CH / PC_BS; ++k) {
        int e = e0 + t + k * PC_BS;
        if (e < NEDGES) atomicAdd(&cnt[erow[e] >> RSHIFT], 1);
    }
    __syncthreads();
    for (int i = t; i < NBKT; i += PC_BS) {
        base_[i] = cnt[i] ? atomicAdd(&bcursor[i], cnt[i]) : 0;
        cnt[i] = 0;
    }
    __syncthreads();
#pragma unroll
    for (int k = 0; k < PC_CH / PC_BS; ++k) {
        int e = e0 + t + k * PC_BS;
        if (e < NEDGES) {
            int row = erow[e], col = ecol[e];
            int b = row >> RSHIFT;
            int pos = base_[b] + atomicAdd(&cnt[b], 1);
            if (pos < BCAP)
                tmp[(size_t)b * BCAP + pos] =
                    ((unsigned)(row & (RPB - 1)) << 18) | (unsigned)col;
        }
    }
}

// per-bucket row counts via LDS (replaces global-atomic k_hist)
__global__ __launch_bounds__(256) void k_rowcount(const unsigned* __restrict__ tmp,
                                                  const int* __restrict__ bcursor,
                                                  int* __restrict__ counts) {
    __shared__ int rc[RPB];
    const int b = blockIdx.x;
    for (int i = threadIdx.x; i < RPB; i += 256) rc[i] = 0;
    __syncthreads();
    int n = bcursor[b]; if (n > BCAP) n = BCAP;
    const unsigned* tp = tmp + (size_t)b * BCAP;
    for (int i = threadIdx.x; i < n; i += 256) atomicAdd(&rc[tp[i] >> 18], 1);
    __syncthreads();
    int rbeg = b * RPB;
    for (int i = threadIdx.x; i < RPB; i += 256)
        if (rbeg + i < N_NODES) counts[rbeg + i] = rc[i];
}

__global__ __launch_bounds__(1024) void k_scan(const int* __restrict__ counts,
                                               int* __restrict__ rowptr) {
    __shared__ int lds[1024];
    const int t = threadIdx.x;
    const int CH = (N_NODES + 1023) / 1024;  // 147
    int beg = t * CH;
    int end = beg + CH; if (end > N_NODES) end = N_NODES;
    int s = 0;
    for (int i = beg; i < end; ++i) s += counts[i];
    lds[t] = s;
    __syncthreads();
    for (int off = 1; off < 1024; off <<= 1) {
        int u = (t >= off) ? lds[t - off] : 0;
        __syncthreads();
        lds[t] += u;
        __syncthreads();
    }
    int run = lds[t] - s;
    for (int i = beg; i < end; ++i) { rowptr[i] = run; run += counts[i]; }
    if (t == 1023) rowptr[N_NODES] = lds[1023];
}

__global__ void k_dinv(const int* __restrict__ counts, float* __restrict__ dinv) {
    int i = blockIdx.x * blockDim.x + threadIdx.x;
    if (i < N_NODES) dinv[i] = 1.0f / (sqrtf((float)counts[i]) + 1e-6f);
}

// place into exact CSR slots; LDS row cursors, writes confined to ~54KB window
__global__ __launch_bounds__(256) void k_place(const unsigned* __restrict__ tmp,
                                               const int* __restrict__ bcursor,
                                               const int* __restrict__ rowptr,
                                               int* __restrict__ csrc) {
    __shared__ int cur[RPB];
    const int b = blockIdx.x;
    for (int i = threadIdx.x; i < RPB; i += 256) cur[i] = 0;
    __syncthreads();
    int n = bcursor[b]; if (n > BCAP) n = BCAP;
    int rbeg = b * RPB;
    const unsigned* tp = tmp + (size_t)b * BCAP;
    for (int i = threadIdx.x; i < n; i += 256) {
        unsigned pk = tp[i];
        int rl = (int)(pk >> 18);
        int col = (int)(pk & 0x3FFFFu);
        int slot = rowptr[rbeg + rl] + atomicAdd(&cur[rl], 1);
        csrc[slot] = col;
    }
}

// ---------------- SpMM ----------------
// hop 1: fp32 E0 -> bf16 out. 16 lanes/row, float4 per lane.
__global__ void k_spmm_f2b(const float* __restrict__ Ein, unsigned short* __restrict__ Eout,
                           const int* __restrict__ rowptr, const int* __restrict__ cols,
                           const float* __restrict__ dinv) {
    int g    = (blockIdx.x * blockDim.x + threadIdx.x) >> 4;
    int lane = threadIdx.x & 15;
    if (g >= N_NODES) return;
    int beg = rowptr[g], end = rowptr[g + 1];
    float4 a0 = make_float4(0.f, 0.f, 0.f, 0.f);
    float4 a1 = make_float4(0.f, 0.f, 0.f, 0.f);
    int j = beg;
    for (; j + 2 <= end; j += 2) {
        int c0 = cols[j], c1 = cols[j + 1];
        float d0 = dinv[c0], d1 = dinv[c1];
        float4 x0 = ((const float4*)(Ein + (size_t)c0 * EMB))[lane];
        float4 x1 = ((const float4*)(Ein + (size_t)c1 * EMB))[lane];
        a0.x = fmaf(d0, x0.x, a0.x); a0.y = fmaf(d0, x0.y, a0.y);
        a0.z = fmaf(d0, x0.z, a0.z); a0.w = fmaf(d0, x0.w, a0.w);
        a1.x = fmaf(d1, x1.x, a1.x); a1.y = fmaf(d1, x1.y, a1.y);
        a1.z = fmaf(d1, x1.z, a1.z); a1.w = fmaf(d1, x1.w, a1.w);
    }
    if (j < end) {
        int c0 = cols[j];
        float d0 = dinv[c0];
        float4 x0 = ((const float4*)(Ein + (size_t)c0 * EMB))[lane];
        a0.x = fmaf(d0, x0.x, a0.x); a0.y = fmaf(d0, x0.y, a0.y);
        a0.z = fmaf(d0, x0.z, a0.z); a0.w = fmaf(d0, x0.w, a0.w);
    }
    float dr = dinv[g];
    ushort4 o;
    o.x = f2b(dr * (a0.x + a1.x)); o.y = f2b(dr * (a0.y + a1.y));
    o.z = f2b(dr * (a0.z + a1.z)); o.w = f2b(dr * (a0.w + a1.w));
    ((ushort4*)(Eout + (size_t)g * EMB))[lane] = o;
}

// hops 2,3: bf16 in -> bf16 out. uint2 (4 bf16) per lane.
__global__ void k_spmm_b2b(const unsigned short* __restrict__ Ein,
                           unsigned short* __restrict__ Eout,
                           const int* __restrict__ rowptr, const int* __restrict__ cols,
                           const float* __restrict__ dinv) {
    int g    = (blockIdx.x * blockDim.x + threadIdx.x) >> 4;
    int lane = threadIdx.x & 15;
    if (g >= N_NODES) return;
    int beg = rowptr[g], end = rowptr[g + 1];
    float4 a0 = make_float4(0.f, 0.f, 0.f, 0.f);
    float4 a1 = make_float4(0.f, 0.f, 0.f, 0.f);
    int j = beg;
    for (; j + 2 <= end; j += 2) {
        int c0 = cols[j], c1 = cols[j + 1];
        float d0 = dinv[c0], d1 = dinv[c1];
        uint2 v0 = ((const uint2*)(Ein + (size_t)c0 * EMB))[lane];
        uint2 v1 = ((const uint2*)(Ein + (size_t)c1 * EMB))[lane];
        a0.x = fmaf(d0, b2f_lo(v0.x), a0.x); a0.y = fmaf(d0, b2f_hi(v0.x), a0.y);
        a0.z = fmaf(d0, b2f_lo(v0.y), a0.z); a0.w = fmaf(d0, b2f_hi(v0.y), a0.w);
        a1.x = fmaf(d1, b2f_lo(v1.x), a1.x); a1.y = fmaf(d1, b2f_hi(v1.x), a1.y);
        a1.z = fmaf(d1, b2f_lo(v1.y), a1.z); a1.w = fmaf(d1, b2f_hi(v1.y), a1.w);
    }
    if (j < end) {
        int c0 = cols[j];
        float d0 = dinv[c0];
        uint2 v0 = ((const uint2*)(Ein + (size_t)c0 * EMB))[lane];
        a0.x = fmaf(d0, b2f_lo(v0.x), a0.x); a0.y = fmaf(d0, b2f_hi(v0.x), a0.y);
        a0.z = fmaf(d0, b2f_lo(v0.y), a0.z); a0.w = fmaf(d0, b2f_hi(v0.y), a0.w);
    }
    float dr = dinv[g];
    ushort4 o;
    o.x = f2b(dr * (a0.x + a1.x)); o.y = f2b(dr * (a0.y + a1.y));
    o.z = f2b(dr * (a0.z + a1.z)); o.w = f2b(dr * (a0.w + a1.w));
    ((ushort4*)(Eout + (size_t)g * EMB))[lane] = o;
}

// ---------------- batch-row gather ----------------

__global__ void k_gather_init(const float* __restrict__ E0, const int* __restrict__ ub,
                              const int* __restrict__ ib, float* __restrict__ U,
                              float* __restrict__ I) {
    int g    = (blockIdx.x * blockDim.x + threadIdx.x) >> 4;
    int lane = threadIdx.x & 15;
    if (g >= 2 * BATCH) return;
    if (g < BATCH) {
        int r = ub[g];
        ((float4*)(U + (size_t)g * EMB))[lane] =
            ((const float4*)(E0 + (size_t)r * EMB))[lane];
    } else {
        int bq = g - BATCH;
        int r = N_USERS + ib[bq];
        ((float4*)(I + (size_t)bq * EMB))[lane] =
            ((const float4*)(E0 + (size_t)r * EMB))[lane];
    }
}

__global__ void k_gather_acc(const unsigned short* __restrict__ E,
                             const int* __restrict__ ub, const int* __restrict__ ib,
                             float* __restrict__ U, float* __restrict__ I) {
    int g    = (blockIdx.x * blockDim.x + threadIdx.x) >> 4;
    int lane = threadIdx.x & 15;
    if (g >= 2 * BATCH) return;
    int r, bq;
    float* dstbuf;
    if (g < BATCH) { r = ub[g]; bq = g; dstbuf = U; }
    else { bq = g - BATCH; r = N_USERS + ib[bq]; dstbuf = I; }
    uint2 v = ((const uint2*)(E + (size_t)r * EMB))[lane];
    float4* dst = (float4*)(dstbuf + (size_t)bq * EMB) + lane;
    float4 a = *dst;
    a.x += b2f_lo(v.x); a.y += b2f_hi(v.x);
    a.z += b2f_lo(v.y); a.w += b2f_hi(v.y);
    *dst = a;
}

// ---------------- final dot ----------------

__global__ void k_dot(const float* __restrict__ U, const float* __restrict__ I,
                      float* __restrict__ out) {
    int g    = (blockIdx.x * blockDim.x + threadIdx.x) >> 4;
    int lane = threadIdx.x & 15;
    if (g >= BATCH) return;
    float4 a = ((const float4*)(U + (size_t)g * EMB))[lane];
    float4 b = ((const float4*)(I + (size_t)g * EMB))[lane];
    float p = a.x * b.x + a.y * b.y + a.z * b.z + a.w * b.w;
    for (int m = 1; m < 16; m <<= 1) p += __shfl_xor(p, m, 64);
    if (lane == 0) out[g] = p * (1.0f / 16.0f);  // 1/(K+1)^2
}

// ---------------- launch ----------------

static inline char* align16(char* p) {
    return (char*)(((uintptr_t)p + 15) & ~(uintptr_t)15);
}

extern "C" void kernel_launch(void* const* d_in, const int* in_sizes, int n_in,
                              void* d_out, int out_size, void* d_ws, size_t ws_size,
                              hipStream_t stream) {
    const float* E0   = (const float*)d_in[0];
    const int*   erow = (const int*)d_in[2];
    const int*   ecol = (const int*)d_in[3];
    const int*   ub   = (const int*)d_in[4];
    const int*   ib   = (const int*)d_in[5];
    float* pred = (float*)d_out;

    char* p = (char*)d_ws;
    unsigned short* Abf = (unsigned short*)p; p = align16(p + (size_t)N_NODES * EMB * 2);
    unsigned short* Bbf = (unsigned short*)p; p = align16(p + (size_t)N_NODES * EMB * 2);
    float* U       = (float*)p;    p = align16(p + (size_t)BATCH * EMB * 4);
    float* I       = (float*)p;    p = align16(p + (size_t)BATCH * EMB * 4);
    int*   counts  = (int*)p;      p = align16(p + (size_t)N_NODES * 4);
    int*   bcursor = (int*)p;      p = align16(p + (size_t)NBKT * 4);
    int*   rowptr  = (int*)p;      p = align16(p + (size_t)(N_NODES + 1) * 4);
    float* dinv    = (float*)p;    p = align16(p + (size_t)N_NODES * 4);
    int*   csrc    = (int*)p;      p = align16(p + (size_t)NEDGES * 4);
    unsigned* tmp  = (unsigned*)p; p = align16(p + (size_t)NBKT * BCAP * 4);

    const int BS = 256;
    // CSR build
    k_zero<<<(NBKT + BS - 1) / BS, BS, 0, stream>>>(bcursor);
    k_partC<<<PC_NWG, PC_BS, 0, stream>>>(erow, ecol, bcursor, tmp);
    k_rowcount<<<NBKT, BS, 0, stream>>>(tmp, bcursor, counts);
    k_scan<<<1, 1024, 0, stream>>>(counts, rowptr);
    k_dinv<<<(N_NODES + BS - 1) / BS, BS, 0, stream>>>(counts, dinv);
    k_place<<<NBKT, BS, 0, stream>>>(tmp, bcursor, rowptr, csrc);

    k_gather_init<<<(2 * BATCH * 16 + BS - 1) / BS, BS, 0, stream>>>(E0, ub, ib, U, I);

    const int spmm_grid = (N_NODES * 16 + BS - 1) / BS;
    const int acc_grid  = (2 * BATCH * 16 + BS - 1) / BS;

    // hop 1: E0(fp32) -> Abf
    k_spmm_f2b<<<spmm_grid, BS, 0, stream>>>(E0, Abf, rowptr, csrc, dinv);
    k_gather_acc<<<acc_grid, BS, 0, stream>>>(Abf, ub, ib, U, I);
    // hop 2: Abf -> Bbf
    k_spmm_b2b<<<spmm_grid, BS, 0, stream>>>(Abf, Bbf, rowptr, csrc, dinv);
    k_gather_acc<<<acc_grid, BS, 0, stream>>>(Bbf, ub, ib, U, I);
    // hop 3: Bbf -> Abf
    k_spmm_b2b<<<spmm_grid, BS, 0, stream>>>(Bbf, Abf, rowptr, csrc, dinv);
    k_gather_acc<<<acc_grid, BS, 0, stream>>>(Abf, ub, ib, U, I);

    // readout
    k_dot<<<(BATCH * 16 + BS - 1) / BS, BS, 0, stream>>>(U, I, pred);
}

// Round 4
// 407.163 us; speedup vs baseline: 3.9609x; 1.6055x over previous
//
#include <hip/hip_runtime.h>

#define N_USERS 100000
#define N_ITEMS 50000
#define N_NODES 150000
#define NEDGES  4000000
#define EMB     64
#define BATCH   16384

#define RSHIFT  9
#define RPB     512                          // rows per bucket
#define NBKT    ((N_NODES + RPB - 1) / RPB)  // 293
#define BCAP    24576                        // max edges/bucket

#define PC_BS   1024
#define PC_CH   16384
#define PC_NWG  ((NEDGES + PC_CH - 1) / PC_CH)  // 245

// ---------------- helpers ----------------

__device__ __forceinline__ unsigned short f2b(float f) {  // fp32 -> bf16 RNE
    unsigned u = __float_as_uint(f);
    return (unsigned short)((u + 0x7FFFu + ((u >> 16) & 1u)) >> 16);
}
__device__ __forceinline__ float b2f_lo(unsigned v) { return __uint_as_float(v << 16); }
__device__ __forceinline__ float b2f_hi(unsigned v) { return __uint_as_float(v & 0xFFFF0000u); }

// ---------------- CSR build ----------------

__global__ void k_zero(int* __restrict__ bcursor) {
    int i = blockIdx.x * blockDim.x + threadIdx.x;
    if (i < NBKT) bcursor[i] = 0;
}

// LDS-staged bucket partition
__global__ __launch_bounds__(PC_BS) void k_partC(const int* __restrict__ erow,
                                                 const int* __restrict__ ecol,
                                                 int* __restrict__ bcursor,
                                                 unsigned* __restrict__ tmp) {
    __shared__ int cnt[NBKT];
    __shared__ int base_[NBKT];
    const int t = threadIdx.x;
    for (int i = t; i < NBKT; i += PC_BS) cnt[i] = 0;
    __syncthreads();
    const int e0 = blockIdx.x * PC_CH;
#pragma unroll
    for (int k = 0; k < PC_CH / PC_BS; ++k) {
        int e = e0 + t + k * PC_BS;
        if (e < NEDGES) atomicAdd(&cnt[erow[e] >> RSHIFT], 1);
    }
    __syncthreads();
    for (int i = t; i < NBKT; i += PC_BS) {
        base_[i] = cnt[i] ? atomicAdd(&bcursor[i], cnt[i]) : 0;
        cnt[i] = 0;
    }
    __syncthreads();
#pragma unroll
    for (int k = 0; k < PC_CH / PC_BS; ++k) {
        int e = e0 + t + k * PC_BS;
        if (e < NEDGES) {
            int row = erow[e], col = ecol[e];
            int b = row >> RSHIFT;
            int pos = base_[b] + atomicAdd(&cnt[b], 1);
            if (pos < BCAP)
                tmp[(size_t)b * BCAP + pos] =
                    ((unsigned)(row & (RPB - 1)) << 18) | (unsigned)col;
        }
    }
}

// scan of per-bucket totals (293 elements, single small block)
__global__ __launch_bounds__(512) void k_bscan(const int* __restrict__ bcursor,
                                               int* __restrict__ bbase,
                                               int* __restrict__ rowptr) {
    __shared__ int s[512];
    const int t = threadIdx.x;
    int v = 0;
    if (t < NBKT) { v = bcursor[t]; if (v > BCAP) v = BCAP; }
    s[t] = v;
    __syncthreads();
    for (int off = 1; off < 512; off <<= 1) {
        int u = (t >= off) ? s[t - off] : 0;
        __syncthreads();
        s[t] += u;
        __syncthreads();
    }
    if (t < NBKT) bbase[t] = s[t] - v;  // exclusive
    if (t == 511) { bbase[NBKT] = s[511]; rowptr[N_NODES] = s[511]; }
}

// per-bucket: row counts in LDS -> 512-wide scan -> rowptr + dinv (fused)
__global__ __launch_bounds__(512) void k_rows(const unsigned* __restrict__ tmp,
                                              const int* __restrict__ bcursor,
                                              const int* __restrict__ bbase,
                                              int* __restrict__ rowptr,
                                              float* __restrict__ dinv) {
    __shared__ int rc[RPB];
    __shared__ int s[RPB];
    const int b = blockIdx.x;
    const int t = threadIdx.x;
    rc[t] = 0;
    __syncthreads();
    int n = bcursor[b]; if (n > BCAP) n = BCAP;
    const unsigned* tp = tmp + (size_t)b * BCAP;
    for (int i = t; i < n; i += 512) atomicAdd(&rc[tp[i] >> 18], 1);
    __syncthreads();
    int my = rc[t];
    s[t] = my;
    __syncthreads();
    for (int off = 1; off < 512; off <<= 1) {
        int u = (t >= off) ? s[t - off] : 0;
        __syncthreads();
        s[t] += u;
        __syncthreads();
    }
    int r = b * RPB + t;
    if (r < N_NODES) {
        rowptr[r] = bbase[b] + (s[t] - my);          // exclusive prefix
        dinv[r] = 1.0f / (sqrtf((float)my) + 1e-6f);
    }
}

// place into exact CSR slots; LDS row cursors
__global__ __launch_bounds__(512) void k_place(const unsigned* __restrict__ tmp,
                                               const int* __restrict__ bcursor,
                                               const int* __restrict__ rowptr,
                                               int* __restrict__ csrc) {
    __shared__ int cur[RPB];
    const int b = blockIdx.x;
    for (int i = threadIdx.x; i < RPB; i += 512) cur[i] = 0;
    __syncthreads();
    int n = bcursor[b]; if (n > BCAP) n = BCAP;
    int rbeg = b * RPB;
    const unsigned* tp = tmp + (size_t)b * BCAP;
    for (int i = threadIdx.x; i < n; i += 512) {
        unsigned pk = tp[i];
        int rl = (int)(pk >> 18);
        int col = (int)(pk & 0x3FFFFu);
        int slot = rowptr[rbeg + rl] + atomicAdd(&cur[rl], 1);
        csrc[slot] = col;
    }
}

// ---------------- SpMM ----------------
// hop 1: fp32 E0 -> bf16 out. 16 lanes/row, float4 per lane.
__global__ void k_spmm_f2b(const float* __restrict__ Ein, unsigned short* __restrict__ Eout,
                           const int* __restrict__ rowptr, const int* __restrict__ cols,
                           const float* __restrict__ dinv) {
    int g    = (blockIdx.x * blockDim.x + threadIdx.x) >> 4;
    int lane = threadIdx.x & 15;
    if (g >= N_NODES) return;
    int beg = rowptr[g], end = rowptr[g + 1];
    float4 a0 = make_float4(0.f, 0.f, 0.f, 0.f);
    float4 a1 = make_float4(0.f, 0.f, 0.f, 0.f);
    int j = beg;
    for (; j + 2 <= end; j += 2) {
        int c0 = cols[j], c1 = cols[j + 1];
        float d0 = dinv[c0], d1 = dinv[c1];
        float4 x0 = ((const float4*)(Ein + (size_t)c0 * EMB))[lane];
        float4 x1 = ((const float4*)(Ein + (size_t)c1 * EMB))[lane];
        a0.x = fmaf(d0, x0.x, a0.x); a0.y = fmaf(d0, x0.y, a0.y);
        a0.z = fmaf(d0, x0.z, a0.z); a0.w = fmaf(d0, x0.w, a0.w);
        a1.x = fmaf(d1, x1.x, a1.x); a1.y = fmaf(d1, x1.y, a1.y);
        a1.z = fmaf(d1, x1.z, a1.z); a1.w = fmaf(d1, x1.w, a1.w);
    }
    if (j < end) {
        int c0 = cols[j];
        float d0 = dinv[c0];
        float4 x0 = ((const float4*)(Ein + (size_t)c0 * EMB))[lane];
        a0.x = fmaf(d0, x0.x, a0.x); a0.y = fmaf(d0, x0.y, a0.y);
        a0.z = fmaf(d0, x0.z, a0.z); a0.w = fmaf(d0, x0.w, a0.w);
    }
    float dr = dinv[g];
    ushort4 o;
    o.x = f2b(dr * (a0.x + a1.x)); o.y = f2b(dr * (a0.y + a1.y));
    o.z = f2b(dr * (a0.z + a1.z)); o.w = f2b(dr * (a0.w + a1.w));
    ((ushort4*)(Eout + (size_t)g * EMB))[lane] = o;
}

// hops 2,3: bf16 in -> bf16 out. uint2 (4 bf16) per lane.
__global__ void k_spmm_b2b(const unsigned short* __restrict__ Ein,
                           unsigned short* __restrict__ Eout,
                           const int* __restrict__ rowptr, const int* __restrict__ cols,
                           const float* __restrict__ dinv) {
    int g    = (blockIdx.x * blockDim.x + threadIdx.x) >> 4;
    int lane = threadIdx.x & 15;
    if (g >= N_NODES) return;
    int beg = rowptr[g], end = rowptr[g + 1];
    float4 a0 = make_float4(0.f, 0.f, 0.f, 0.f);
    float4 a1 = make_float4(0.f, 0.f, 0.f, 0.f);
    int j = beg;
    for (; j + 2 <= end; j += 2) {
        int c0 = cols[j], c1 = cols[j + 1];
        float d0 = dinv[c0], d1 = dinv[c1];
        uint2 v0 = ((const uint2*)(Ein + (size_t)c0 * EMB))[lane];
        uint2 v1 = ((const uint2*)(Ein + (size_t)c1 * EMB))[lane];
        a0.x = fmaf(d0, b2f_lo(v0.x), a0.x); a0.y = fmaf(d0, b2f_hi(v0.x), a0.y);
        a0.z = fmaf(d0, b2f_lo(v0.y), a0.z); a0.w = fmaf(d0, b2f_hi(v0.y), a0.w);
        a1.x = fmaf(d1, b2f_lo(v1.x), a1.x); a1.y = fmaf(d1, b2f_hi(v1.x), a1.y);
        a1.z = fmaf(d1, b2f_lo(v1.y), a1.z); a1.w = fmaf(d1, b2f_hi(v1.y), a1.w);
    }
    if (j < end) {
        int c0 = cols[j];
        float d0 = dinv[c0];
        uint2 v0 = ((const uint2*)(Ein + (size_t)c0 * EMB))[lane];
        a0.x = fmaf(d0, b2f_lo(v0.x), a0.x); a0.y = fmaf(d0, b2f_hi(v0.x), a0.y);
        a0.z = fmaf(d0, b2f_lo(v0.y), a0.z); a0.w = fmaf(d0, b2f_hi(v0.y), a0.w);
    }
    float dr = dinv[g];
    ushort4 o;
    o.x = f2b(dr * (a0.x + a1.x)); o.y = f2b(dr * (a0.y + a1.y));
    o.z = f2b(dr * (a0.z + a1.z)); o.w = f2b(dr * (a0.w + a1.w));
    ((ushort4*)(Eout + (size_t)g * EMB))[lane] = o;
}

// ---------------- batch-row gather ----------------

__global__ void k_gather_init(const float* __restrict__ E0, const int* __restrict__ ub,
                              const int* __restrict__ ib, float* __restrict__ U,
                              float* __restrict__ I) {
    int g    = (blockIdx.x * blockDim.x + threadIdx.x) >> 4;
    int lane = threadIdx.x & 15;
    if (g >= 2 * BATCH) return;
    if (g < BATCH) {
        int r = ub[g];
        ((float4*)(U + (size_t)g * EMB))[lane] =
            ((const float4*)(E0 + (size_t)r * EMB))[lane];
    } else {
        int bq = g - BATCH;
        int r = N_USERS + ib[bq];
        ((float4*)(I + (size_t)bq * EMB))[lane] =
            ((const float4*)(E0 + (size_t)r * EMB))[lane];
    }
}

__global__ void k_gather_acc(const unsigned short* __restrict__ E,
                             const int* __restrict__ ub, const int* __restrict__ ib,
                             float* __restrict__ U, float* __restrict__ I) {
    int g    = (blockIdx.x * blockDim.x + threadIdx.x) >> 4;
    int lane = threadIdx.x & 15;
    if (g >= 2 * BATCH) return;
    int r, bq;
    float* dstbuf;
    if (g < BATCH) { r = ub[g]; bq = g; dstbuf = U; }
    else { bq = g - BATCH; r = N_USERS + ib[bq]; dstbuf = I; }
    uint2 v = ((const uint2*)(E + (size_t)r * EMB))[lane];
    float4* dst = (float4*)(dstbuf + (size_t)bq * EMB) + lane;
    float4 a = *dst;
    a.x += b2f_lo(v.x); a.y += b2f_hi(v.x);
    a.z += b2f_lo(v.y); a.w += b2f_hi(v.y);
    *dst = a;
}

// ---------------- final dot ----------------

__global__ void k_dot(const float* __restrict__ U, const float* __restrict__ I,
                      float* __restrict__ out) {
    int g    = (blockIdx.x * blockDim.x + threadIdx.x) >> 4;
    int lane = threadIdx.x & 15;
    if (g >= BATCH) return;
    float4 a = ((const float4*)(U + (size_t)g * EMB))[lane];
    float4 b = ((const float4*)(I + (size_t)g * EMB))[lane];
    float p = a.x * b.x + a.y * b.y + a.z * b.z + a.w * b.w;
    for (int m = 1; m < 16; m <<= 1) p += __shfl_xor(p, m, 64);
    if (lane == 0) out[g] = p * (1.0f / 16.0f);  // 1/(K+1)^2
}

// ---------------- launch ----------------

static inline char* align16(char* p) {
    return (char*)(((uintptr_t)p + 15) & ~(uintptr_t)15);
}

extern "C" void kernel_launch(void* const* d_in, const int* in_sizes, int n_in,
                              void* d_out, int out_size, void* d_ws, size_t ws_size,
                              hipStream_t stream) {
    const float* E0   = (const float*)d_in[0];
    const int*   erow = (const int*)d_in[2];
    const int*   ecol = (const int*)d_in[3];
    const int*   ub   = (const int*)d_in[4];
    const int*   ib   = (const int*)d_in[5];
    float* pred = (float*)d_out;

    char* p = (char*)d_ws;
    unsigned short* Abf = (unsigned short*)p; p = align16(p + (size_t)N_NODES * EMB * 2);
    unsigned short* Bbf = (unsigned short*)p; p = align16(p + (size_t)N_NODES * EMB * 2);
    float* U       = (float*)p;    p = align16(p + (size_t)BATCH * EMB * 4);
    float* I       = (float*)p;    p = align16(p + (size_t)BATCH * EMB * 4);
    int*   bcursor = (int*)p;      p = align16(p + (size_t)NBKT * 4);
    int*   bbase   = (int*)p;      p = align16(p + (size_t)(NBKT + 1) * 4);
    int*   rowptr  = (int*)p;      p = align16(p + (size_t)(N_NODES + 1) * 4);
    float* dinv    = (float*)p;    p = align16(p + (size_t)N_NODES * 4);
    int*   csrc    = (int*)p;      p = align16(p + (size_t)NEDGES * 4);
    unsigned* tmp  = (unsigned*)p; p = align16(p + (size_t)NBKT * BCAP * 4);

    const int BS = 256;
    // CSR build
    k_zero<<<(NBKT + BS - 1) / BS, BS, 0, stream>>>(bcursor);
    k_partC<<<PC_NWG, PC_BS, 0, stream>>>(erow, ecol, bcursor, tmp);
    k_bscan<<<1, 512, 0, stream>>>(bcursor, bbase, rowptr);
    k_rows<<<NBKT, 512, 0, stream>>>(tmp, bcursor, bbase, rowptr, dinv);
    k_place<<<NBKT, 512, 0, stream>>>(tmp, bcursor, rowptr, csrc);

    k_gather_init<<<(2 * BATCH * 16 + BS - 1) / BS, BS, 0, stream>>>(E0, ub, ib, U, I);

    const int spmm_grid = (N_NODES * 16 + BS - 1) / BS;
    const int acc_grid  = (2 * BATCH * 16 + BS - 1) / BS;

    // hop 1: E0(fp32) -> Abf
    k_spmm_f2b<<<spmm_grid, BS, 0, stream>>>(E0, Abf, rowptr, csrc, dinv);
    k_gather_acc<<<acc_grid, BS, 0, stream>>>(Abf, ub, ib, U, I);
    // hop 2: Abf -> Bbf
    k_spmm_b2b<<<spmm_grid, BS, 0, stream>>>(Abf, Bbf, rowptr, csrc, dinv);
    k_gather_acc<<<acc_grid, BS, 0, stream>>>(Bbf, ub, ib, U, I);
    // hop 3: Bbf -> Abf
    k_spmm_b2b<<<spmm_grid, BS, 0, stream>>>(Bbf, Abf, rowptr, csrc, dinv);
    k_gather_acc<<<acc_grid, BS, 0, stream>>>(Abf, ub, ib, U, I);

    // readout
    k_dot<<<(BATCH * 16 + BS - 1) / BS, BS, 0, stream>>>(U, I, pred);
}

// Round 5
// 318.437 us; speedup vs baseline: 5.0645x; 1.2786x over previous
//
#include <hip/hip_runtime.h>

#define N_USERS 100000
#define N_ITEMS 50000
#define N_NODES 150000
#define NEDGES  4000000
#define EMB     64
#define BATCH   16384

#define RSHIFT  9
#define RPB     512                          // rows per bucket
#define NBKT    ((N_NODES + RPB - 1) / RPB)  // 293
#define BCAP    24576                        // max edges/bucket

#define PC_BS   1024
#define PC_CH   16384
#define PC_NWG  ((NEDGES + PC_CH - 1) / PC_CH)  // 245

// ---------------- helpers ----------------

__device__ __forceinline__ unsigned short f2b(float f) {  // fp32 -> bf16 RNE
    unsigned u = __float_as_uint(f);
    return (unsigned short)((u + 0x7FFFu + ((u >> 16) & 1u)) >> 16);
}
__device__ __forceinline__ float b2f_lo(unsigned v) { return __uint_as_float(v << 16); }
__device__ __forceinline__ float b2f_hi(unsigned v) { return __uint_as_float(v & 0xFFFF0000u); }

// ---------------- CSR build ----------------

__global__ void k_zero(int* __restrict__ bcursor) {
    int i = blockIdx.x * blockDim.x + threadIdx.x;
    if (i < NBKT) bcursor[i] = 0;
}

// LDS-staged bucket partition
__global__ __launch_bounds__(PC_BS) void k_partC(const int* __restrict__ erow,
                                                 const int* __restrict__ ecol,
                                                 int* __restrict__ bcursor,
                                                 unsigned* __restrict__ tmp) {
    __shared__ int cnt[NBKT];
    __shared__ int base_[NBKT];
    const int t = threadIdx.x;
    for (int i = t; i < NBKT; i += PC_BS) cnt[i] = 0;
    __syncthreads();
    const int e0 = blockIdx.x * PC_CH;
#pragma unroll
    for (int k = 0; k < PC_CH / PC_BS; ++k) {
        int e = e0 + t + k * PC_BS;
        if (e < NEDGES) atomicAdd(&cnt[erow[e] >> RSHIFT], 1);
    }
    __syncthreads();
    for (int i = t; i < NBKT; i += PC_BS) {
        base_[i] = cnt[i] ? atomicAdd(&bcursor[i], cnt[i]) : 0;
        cnt[i] = 0;
    }
    __syncthreads();
#pragma unroll
    for (int k = 0; k < PC_CH / PC_BS; ++k) {
        int e = e0 + t + k * PC_BS;
        if (e < NEDGES) {
            int row = erow[e], col = ecol[e];
            int b = row >> RSHIFT;
            int pos = base_[b] + atomicAdd(&cnt[b], 1);
            if (pos < BCAP)
                tmp[(size_t)b * BCAP + pos] =
                    ((unsigned)(row & (RPB - 1)) << 18) | (unsigned)col;
        }
    }
}

// scan of per-bucket totals (293 elements, single small block)
__global__ __launch_bounds__(512) void k_bscan(const int* __restrict__ bcursor,
                                               int* __restrict__ bbase,
                                               int* __restrict__ rowptr) {
    __shared__ int s[512];
    const int t = threadIdx.x;
    int v = 0;
    if (t < NBKT) { v = bcursor[t]; if (v > BCAP) v = BCAP; }
    s[t] = v;
    __syncthreads();
    for (int off = 1; off < 512; off <<= 1) {
        int u = (t >= off) ? s[t - off] : 0;
        __syncthreads();
        s[t] += u;
        __syncthreads();
    }
    if (t < NBKT) bbase[t] = s[t] - v;  // exclusive
    if (t == 511) { bbase[NBKT] = s[511]; rowptr[N_NODES] = s[511]; }
}

// fused: per-bucket row count (LDS) -> LDS scan -> rowptr+dinv -> place edges
__global__ __launch_bounds__(512) void k_rows_place(const unsigned* __restrict__ tmp,
                                                    const int* __restrict__ bcursor,
                                                    const int* __restrict__ bbase,
                                                    int* __restrict__ rowptr,
                                                    float* __restrict__ dinv,
                                                    int* __restrict__ csrc) {
    __shared__ int rc[RPB];
    __shared__ int pre[RPB];
    const int b = blockIdx.x;
    const int t = threadIdx.x;
    rc[t] = 0;
    __syncthreads();
    int n = bcursor[b]; if (n > BCAP) n = BCAP;
    const unsigned* tp = tmp + (size_t)b * BCAP;
    for (int i = t; i < n; i += 512) atomicAdd(&rc[tp[i] >> 18], 1);
    __syncthreads();
    int my = rc[t];
    pre[t] = my;
    __syncthreads();
    for (int off = 1; off < 512; off <<= 1) {
        int u = (t >= off) ? pre[t - off] : 0;
        __syncthreads();
        pre[t] += u;
        __syncthreads();
    }
    int ex   = pre[t] - my;          // exclusive prefix within bucket
    int base = bbase[b];
    int r = b * RPB + t;
    if (r < N_NODES) {
        rowptr[r] = base + ex;
        dinv[r]   = 1.0f / (sqrtf((float)my) + 1e-6f);
    }
    __syncthreads();
    rc[t] = base + ex;               // absolute write cursor per row
    __syncthreads();
    for (int i = t; i < n; i += 512) {
        unsigned pk = tp[i];
        int slot = atomicAdd(&rc[pk >> 18], 1);
        csrc[slot] = (int)(pk & 0x3FFFFu);
    }
}

// E0 fp32 -> bf16 (streaming)
__global__ void k_cast(const float* __restrict__ E0, unsigned short* __restrict__ E0bf) {
    int i = blockIdx.x * blockDim.x + threadIdx.x;  // one float4 per thread
    const int total = N_NODES * EMB / 4;
    if (i >= total) return;
    float4 v = ((const float4*)E0)[i];
    ushort4 o;
    o.x = f2b(v.x); o.y = f2b(v.y); o.z = f2b(v.z); o.w = f2b(v.w);
    ((ushort4*)E0bf)[i] = o;
}

// ---------------- SpMM: bf16 in -> bf16 out, 16 lanes/row, unroll x4 --------

__global__ void k_spmm_b2b(const unsigned short* __restrict__ Ein,
                           unsigned short* __restrict__ Eout,
                           const int* __restrict__ rowptr, const int* __restrict__ cols,
                           const float* __restrict__ dinv) {
    int g    = (blockIdx.x * blockDim.x + threadIdx.x) >> 4;
    int lane = threadIdx.x & 15;
    if (g >= N_NODES) return;
    int beg = rowptr[g], end = rowptr[g + 1];
    float4 a0 = make_float4(0.f, 0.f, 0.f, 0.f);
    float4 a1 = make_float4(0.f, 0.f, 0.f, 0.f);
    float4 a2 = make_float4(0.f, 0.f, 0.f, 0.f);
    float4 a3 = make_float4(0.f, 0.f, 0.f, 0.f);
    int j = beg;
    for (; j + 4 <= end; j += 4) {
        int c0 = cols[j], c1 = cols[j + 1], c2 = cols[j + 2], c3 = cols[j + 3];
        float d0 = dinv[c0], d1 = dinv[c1], d2 = dinv[c2], d3 = dinv[c3];
        uint2 v0 = ((const uint2*)(Ein + (size_t)c0 * EMB))[lane];
        uint2 v1 = ((const uint2*)(Ein + (size_t)c1 * EMB))[lane];
        uint2 v2 = ((const uint2*)(Ein + (size_t)c2 * EMB))[lane];
        uint2 v3 = ((const uint2*)(Ein + (size_t)c3 * EMB))[lane];
        a0.x = fmaf(d0, b2f_lo(v0.x), a0.x); a0.y = fmaf(d0, b2f_hi(v0.x), a0.y);
        a0.z = fmaf(d0, b2f_lo(v0.y), a0.z); a0.w = fmaf(d0, b2f_hi(v0.y), a0.w);
        a1.x = fmaf(d1, b2f_lo(v1.x), a1.x); a1.y = fmaf(d1, b2f_hi(v1.x), a1.y);
        a1.z = fmaf(d1, b2f_lo(v1.y), a1.z); a1.w = fmaf(d1, b2f_hi(v1.y), a1.w);
        a2.x = fmaf(d2, b2f_lo(v2.x), a2.x); a2.y = fmaf(d2, b2f_hi(v2.x), a2.y);
        a2.z = fmaf(d2, b2f_lo(v2.y), a2.z); a2.w = fmaf(d2, b2f_hi(v2.y), a2.w);
        a3.x = fmaf(d3, b2f_lo(v3.x), a3.x); a3.y = fmaf(d3, b2f_hi(v3.x), a3.y);
        a3.z = fmaf(d3, b2f_lo(v3.y), a3.z); a3.w = fmaf(d3, b2f_hi(v3.y), a3.w);
    }
    for (; j < end; ++j) {
        int c0 = cols[j];
        float d0 = dinv[c0];
        uint2 v0 = ((const uint2*)(Ein + (size_t)c0 * EMB))[lane];
        a0.x = fmaf(d0, b2f_lo(v0.x), a0.x); a0.y = fmaf(d0, b2f_hi(v0.x), a0.y);
        a0.z = fmaf(d0, b2f_lo(v0.y), a0.z); a0.w = fmaf(d0, b2f_hi(v0.y), a0.w);
    }
    float dr = dinv[g];
    ushort4 o;
    o.x = f2b(dr * ((a0.x + a1.x) + (a2.x + a3.x)));
    o.y = f2b(dr * ((a0.y + a1.y) + (a2.y + a3.y)));
    o.z = f2b(dr * ((a0.z + a1.z) + (a2.z + a3.z)));
    o.w = f2b(dr * ((a0.w + a1.w) + (a2.w + a3.w)));
    ((ushort4*)(Eout + (size_t)g * EMB))[lane] = o;
}

// ---------------- batch-row gather ----------------

__global__ void k_gather_init(const float* __restrict__ E0, const int* __restrict__ ub,
                              const int* __restrict__ ib, float* __restrict__ U,
                              float* __restrict__ I) {
    int g    = (blockIdx.x * blockDim.x + threadIdx.x) >> 4;
    int lane = threadIdx.x & 15;
    if (g >= 2 * BATCH) return;
    if (g < BATCH) {
        int r = ub[g];
        ((float4*)(U + (size_t)g * EMB))[lane] =
            ((const float4*)(E0 + (size_t)r * EMB))[lane];
    } else {
        int bq = g - BATCH;
        int r = N_USERS + ib[bq];
        ((float4*)(I + (size_t)bq * EMB))[lane] =
            ((const float4*)(E0 + (size_t)r * EMB))[lane];
    }
}

__global__ void k_gather_acc(const unsigned short* __restrict__ E,
                             const int* __restrict__ ub, const int* __restrict__ ib,
                             float* __restrict__ U, float* __restrict__ I) {
    int g    = (blockIdx.x * blockDim.x + threadIdx.x) >> 4;
    int lane = threadIdx.x & 15;
    if (g >= 2 * BATCH) return;
    int r, bq;
    float* dstbuf;
    if (g < BATCH) { r = ub[g]; bq = g; dstbuf = U; }
    else { bq = g - BATCH; r = N_USERS + ib[bq]; dstbuf = I; }
    uint2 v = ((const uint2*)(E + (size_t)r * EMB))[lane];
    float4* dst = (float4*)(dstbuf + (size_t)bq * EMB) + lane;
    float4 a = *dst;
    a.x += b2f_lo(v.x); a.y += b2f_hi(v.x);
    a.z += b2f_lo(v.y); a.w += b2f_hi(v.y);
    *dst = a;
}

// ---------------- final dot ----------------

__global__ void k_dot(const float* __restrict__ U, const float* __restrict__ I,
                      float* __restrict__ out) {
    int g    = (blockIdx.x * blockDim.x + threadIdx.x) >> 4;
    int lane = threadIdx.x & 15;
    if (g >= BATCH) return;
    float4 a = ((const float4*)(U + (size_t)g * EMB))[lane];
    float4 b = ((const float4*)(I + (size_t)g * EMB))[lane];
    float p = a.x * b.x + a.y * b.y + a.z * b.z + a.w * b.w;
    for (int m = 1; m < 16; m <<= 1) p += __shfl_xor(p, m, 64);
    if (lane == 0) out[g] = p * (1.0f / 16.0f);  // 1/(K+1)^2
}

// ---------------- launch ----------------

static inline char* align16(char* p) {
    return (char*)(((uintptr_t)p + 15) & ~(uintptr_t)15);
}

extern "C" void kernel_launch(void* const* d_in, const int* in_sizes, int n_in,
                              void* d_out, int out_size, void* d_ws, size_t ws_size,
                              hipStream_t stream) {
    const float* E0   = (const float*)d_in[0];
    const int*   erow = (const int*)d_in[2];
    const int*   ecol = (const int*)d_in[3];
    const int*   ub   = (const int*)d_in[4];
    const int*   ib   = (const int*)d_in[5];
    float* pred = (float*)d_out;

    char* p = (char*)d_ws;
    unsigned short* E0bf = (unsigned short*)p; p = align16(p + (size_t)N_NODES * EMB * 2);
    unsigned short* Abf  = (unsigned short*)p; p = align16(p + (size_t)N_NODES * EMB * 2);
    unsigned short* Bbf  = (unsigned short*)p; p = align16(p + (size_t)N_NODES * EMB * 2);
    float* U       = (float*)p;    p = align16(p + (size_t)BATCH * EMB * 4);
    float* I       = (float*)p;    p = align16(p + (size_t)BATCH * EMB * 4);
    int*   bcursor = (int*)p;      p = align16(p + (size_t)NBKT * 4);
    int*   bbase   = (int*)p;      p = align16(p + (size_t)(NBKT + 1) * 4);
    int*   rowptr  = (int*)p;      p = align16(p + (size_t)(N_NODES + 1) * 4);
    float* dinv    = (float*)p;    p = align16(p + (size_t)N_NODES * 4);
    int*   csrc    = (int*)p;      p = align16(p + (size_t)NEDGES * 4);
    unsigned* tmp  = (unsigned*)p; p = align16(p + (size_t)NBKT * BCAP * 4);

    const int BS = 256;
    // CSR build + cast
    k_zero<<<(NBKT + BS - 1) / BS, BS, 0, stream>>>(bcursor);
    k_partC<<<PC_NWG, PC_BS, 0, stream>>>(erow, ecol, bcursor, tmp);
    k_cast<<<(N_NODES * EMB / 4 + BS - 1) / BS, BS, 0, stream>>>(E0, E0bf);
    k_bscan<<<1, 512, 0, stream>>>(bcursor, bbase, rowptr);
    k_rows_place<<<NBKT, 512, 0, stream>>>(tmp, bcursor, bbase, rowptr, dinv, csrc);

    k_gather_init<<<(2 * BATCH * 16 + BS - 1) / BS, BS, 0, stream>>>(E0, ub, ib, U, I);

    const int spmm_grid = (N_NODES * 16 + BS - 1) / BS;
    const int acc_grid  = (2 * BATCH * 16 + BS - 1) / BS;

    // hop 1: E0bf -> Abf
    k_spmm_b2b<<<spmm_grid, BS, 0, stream>>>(E0bf, Abf, rowptr, csrc, dinv);
    k_gather_acc<<<acc_grid, BS, 0, stream>>>(Abf, ub, ib, U, I);
    // hop 2: Abf -> Bbf
    k_spmm_b2b<<<spmm_grid, BS, 0, stream>>>(Abf, Bbf, rowptr, csrc, dinv);
    k_gather_acc<<<acc_grid, BS, 0, stream>>>(Bbf, ub, ib, U, I);
    // hop 3: Bbf -> Abf
    k_spmm_b2b<<<spmm_grid, BS, 0, stream>>>(Bbf, Abf, rowptr, csrc, dinv);
    k_gather_acc<<<acc_grid, BS, 0, stream>>>(Abf, ub, ib, U, I);

    // readout
    k_dot<<<(BATCH * 16 + BS - 1) / BS, BS, 0, stream>>>(U, I, pred);
}

// Round 6
// 292.912 us; speedup vs baseline: 5.5058x; 1.0871x over previous
//
#include <hip/hip_runtime.h>

#define N_USERS 100000
#define N_ITEMS 50000
#define N_NODES 150000
#define NEDGES  4000000
#define EMB     64
#define BATCH   16384

#define RSHIFT  9
#define RPB     512                          // rows per bucket
#define NBKT    ((N_NODES + RPB - 1) / RPB)  // 293
#define BCAP    24576                        // max edges/bucket

#define PC_BS   1024
#define PC_CH   16384
#define PC_EPT  (PC_CH / PC_BS)                 // 16 edges/thread
#define PC_NWG  ((NEDGES + PC_CH - 1) / PC_CH)  // 245

// ---------------- helpers ----------------

__device__ __forceinline__ unsigned short f2b(float f) {  // fp32 -> bf16 RNE
    unsigned u = __float_as_uint(f);
    return (unsigned short)((u + 0x7FFFu + ((u >> 16) & 1u)) >> 16);
}
__device__ __forceinline__ float b2f_lo(unsigned v) { return __uint_as_float(v << 16); }
__device__ __forceinline__ float b2f_hi(unsigned v) { return __uint_as_float(v & 0xFFFF0000u); }

__device__ __forceinline__ void acc8(float* a, uint4 v) {
    a[0] += b2f_lo(v.x); a[1] += b2f_hi(v.x);
    a[2] += b2f_lo(v.y); a[3] += b2f_hi(v.y);
    a[4] += b2f_lo(v.z); a[5] += b2f_hi(v.z);
    a[6] += b2f_lo(v.w); a[7] += b2f_hi(v.w);
}

// ---------------- CSR build ----------------

__global__ void k_zero(int* __restrict__ bcursor) {
    int i = blockIdx.x * blockDim.x + threadIdx.x;
    if (i < NBKT) bcursor[i] = 0;
}

// LDS-staged bucket partition; edges cached in registers across the two passes
__global__ __launch_bounds__(PC_BS) void k_partC(const int* __restrict__ erow,
                                                 const int* __restrict__ ecol,
                                                 int* __restrict__ bcursor,
                                                 unsigned* __restrict__ tmp) {
    __shared__ int cnt[NBKT];
    __shared__ int base_[NBKT];
    const int t = threadIdx.x;
    for (int i = t; i < NBKT; i += PC_BS) cnt[i] = 0;
    __syncthreads();
    const int e0 = blockIdx.x * PC_CH;
    int rr[PC_EPT], cc[PC_EPT];
#pragma unroll
    for (int k = 0; k < PC_EPT; ++k) {
        int e = e0 + t + k * PC_BS;
        if (e < NEDGES) {
            rr[k] = erow[e];
            cc[k] = ecol[e];
            atomicAdd(&cnt[rr[k] >> RSHIFT], 1);
        } else rr[k] = -1;
    }
    __syncthreads();
    for (int i = t; i < NBKT; i += PC_BS) {
        base_[i] = cnt[i] ? atomicAdd(&bcursor[i], cnt[i]) : 0;
        cnt[i] = 0;
    }
    __syncthreads();
#pragma unroll
    for (int k = 0; k < PC_EPT; ++k) {
        if (rr[k] >= 0) {
            int b = rr[k] >> RSHIFT;
            int pos = base_[b] + atomicAdd(&cnt[b], 1);
            if (pos < BCAP)
                tmp[(size_t)b * BCAP + pos] =
                    ((unsigned)(rr[k] & (RPB - 1)) << 18) | (unsigned)cc[k];
        }
    }
}

// scan of per-bucket totals
__global__ __launch_bounds__(512) void k_bscan(const int* __restrict__ bcursor,
                                               int* __restrict__ bbase,
                                               int* __restrict__ rowptr) {
    __shared__ int s[512];
    const int t = threadIdx.x;
    int v = 0;
    if (t < NBKT) { v = bcursor[t]; if (v > BCAP) v = BCAP; }
    s[t] = v;
    __syncthreads();
    for (int off = 1; off < 512; off <<= 1) {
        int u = (t >= off) ? s[t - off] : 0;
        __syncthreads();
        s[t] += u;
        __syncthreads();
    }
    if (t < NBKT) bbase[t] = s[t] - v;  // exclusive
    if (t == 511) { bbase[NBKT] = s[511]; rowptr[N_NODES] = s[511]; }
}

// fused: row count (LDS) -> LDS scan -> rowptr + dinv/s2/srt -> place edges
__global__ __launch_bounds__(512) void k_rows_place(const unsigned* __restrict__ tmp,
                                                    const int* __restrict__ bcursor,
                                                    const int* __restrict__ bbase,
                                                    int* __restrict__ rowptr,
                                                    float* __restrict__ dinv,
                                                    float* __restrict__ s2,
                                                    float* __restrict__ srt,
                                                    int* __restrict__ csrc) {
    __shared__ int rc[RPB];
    __shared__ int pre[RPB];
    const int b = blockIdx.x;
    const int t = threadIdx.x;
    rc[t] = 0;
    __syncthreads();
    int n = bcursor[b]; if (n > BCAP) n = BCAP;
    const unsigned* tp = tmp + (size_t)b * BCAP;
    for (int i = t; i < n; i += 512) atomicAdd(&rc[tp[i] >> 18], 1);
    __syncthreads();
    int my = rc[t];
    pre[t] = my;
    __syncthreads();
    for (int off = 1; off < 512; off <<= 1) {
        int u = (t >= off) ? pre[t - off] : 0;
        __syncthreads();
        pre[t] += u;
        __syncthreads();
    }
    int ex   = pre[t] - my;
    int base = bbase[b];
    int r = b * RPB + t;
    if (r < N_NODES) {
        float sr = sqrtf((float)my) + 1e-6f;   // 1/dinv
        float dv = 1.0f / sr;
        rowptr[r] = base + ex;
        dinv[r] = dv;
        s2[r]   = dv * dv;
        srt[r]  = sr;
    }
    __syncthreads();
    rc[t] = base + ex;               // absolute write cursor per row
    __syncthreads();
    for (int i = t; i < n; i += 512) {
        unsigned pk = tp[i];
        int slot = atomicAdd(&rc[pk >> 18], 1);
        csrc[slot] = (int)(pk & 0x3FFFFu);
    }
}

// F0 = dinv * E0, bf16
__global__ void k_cast(const float* __restrict__ E0, const float* __restrict__ dinv,
                       unsigned short* __restrict__ F0) {
    int i = blockIdx.x * blockDim.x + threadIdx.x;  // one float4 per thread
    const int total = N_NODES * EMB / 4;
    if (i >= total) return;
    float dv = dinv[i >> 4];
    float4 v = ((const float4*)E0)[i];
    ushort4 o;
    o.x = f2b(dv * v.x); o.y = f2b(dv * v.y);
    o.z = f2b(dv * v.z); o.w = f2b(dv * v.w);
    ((ushort4*)F0)[i] = o;
}

// ---------------- SpMM: F_out[r] = s2[r] * sum_{c in N(r)} F_in[c] ----------
// 8 lanes/row, uint4 (8 bf16) per lane, pure adds in the inner loop.

__global__ __launch_bounds__(256) void k_spmm(const unsigned short* __restrict__ Fin,
                                              unsigned short* __restrict__ Fout,
                                              const int* __restrict__ rowptr,
                                              const int* __restrict__ cols,
                                              const float* __restrict__ s2) {
    int g    = (blockIdx.x * blockDim.x + threadIdx.x) >> 3;
    int lane = threadIdx.x & 7;
    if (g >= N_NODES) return;
    int beg = rowptr[g], end = rowptr[g + 1];
    float A[8] = {0,0,0,0,0,0,0,0};
    float B[8] = {0,0,0,0,0,0,0,0};
    int j = beg;
    // align j to 4 for int4 column loads
    int nscal = (4 - (j & 3)) & 3;
    for (int k = 0; k < nscal && j < end; ++k, ++j) {
        uint4 v = ((const uint4*)(Fin + (size_t)cols[j] * EMB))[lane];
        acc8(A, v);
    }
    for (; j + 4 <= end; j += 4) {
        int4 c = *(const int4*)(cols + j);
        uint4 v0 = ((const uint4*)(Fin + (size_t)c.x * EMB))[lane];
        uint4 v1 = ((const uint4*)(Fin + (size_t)c.y * EMB))[lane];
        uint4 v2 = ((const uint4*)(Fin + (size_t)c.z * EMB))[lane];
        uint4 v3 = ((const uint4*)(Fin + (size_t)c.w * EMB))[lane];
        acc8(A, v0); acc8(B, v1); acc8(A, v2); acc8(B, v3);
    }
    for (; j < end; ++j) {
        uint4 v = ((const uint4*)(Fin + (size_t)cols[j] * EMB))[lane];
        acc8(A, v);
    }
    float s = s2[g];
    unsigned o0 = ((unsigned)f2b(s * (A[1] + B[1])) << 16) | f2b(s * (A[0] + B[0]));
    unsigned o1 = ((unsigned)f2b(s * (A[3] + B[3])) << 16) | f2b(s * (A[2] + B[2]));
    unsigned o2 = ((unsigned)f2b(s * (A[5] + B[5])) << 16) | f2b(s * (A[4] + B[4]));
    unsigned o3 = ((unsigned)f2b(s * (A[7] + B[7])) << 16) | f2b(s * (A[6] + B[6]));
    uint4 o = make_uint4(o0, o1, o2, o3);
    ((uint4*)(Fout + (size_t)g * EMB))[lane] = o;
}

// ---------------- batch-row gather ----------------

__global__ void k_gather_init(const float* __restrict__ E0, const int* __restrict__ ub,
                              const int* __restrict__ ib, float* __restrict__ U,
                              float* __restrict__ I) {
    int g    = (blockIdx.x * blockDim.x + threadIdx.x) >> 4;
    int lane = threadIdx.x & 15;
    if (g >= 2 * BATCH) return;
    if (g < BATCH) {
        int r = ub[g];
        ((float4*)(U + (size_t)g * EMB))[lane] =
            ((const float4*)(E0 + (size_t)r * EMB))[lane];
    } else {
        int bq = g - BATCH;
        int r = N_USERS + ib[bq];
        ((float4*)(I + (size_t)bq * EMB))[lane] =
            ((const float4*)(E0 + (size_t)r * EMB))[lane];
    }
}

// U/I += F[r] * srt[r]   (recovers E_i[r] = F_i[r]/dinv[r])
__global__ void k_gather_acc(const unsigned short* __restrict__ F,
                             const float* __restrict__ srt,
                             const int* __restrict__ ub, const int* __restrict__ ib,
                             float* __restrict__ U, float* __restrict__ I) {
    int g    = (blockIdx.x * blockDim.x + threadIdx.x) >> 4;
    int lane = threadIdx.x & 15;
    if (g >= 2 * BATCH) return;
    int r, bq;
    float* dstbuf;
    if (g < BATCH) { r = ub[g]; bq = g; dstbuf = U; }
    else { bq = g - BATCH; r = N_USERS + ib[bq]; dstbuf = I; }
    float sr = srt[r];
    uint2 v = ((const uint2*)(F + (size_t)r * EMB))[lane];
    float4* dst = (float4*)(dstbuf + (size_t)bq * EMB) + lane;
    float4 a = *dst;
    a.x = fmaf(sr, b2f_lo(v.x), a.x); a.y = fmaf(sr, b2f_hi(v.x), a.y);
    a.z = fmaf(sr, b2f_lo(v.y), a.z); a.w = fmaf(sr, b2f_hi(v.y), a.w);
    *dst = a;
}

// ---------------- final dot ----------------

__global__ void k_dot(const float* __restrict__ U, const float* __restrict__ I,
                      float* __restrict__ out) {
    int g    = (blockIdx.x * blockDim.x + threadIdx.x) >> 4;
    int lane = threadIdx.x & 15;
    if (g >= BATCH) return;
    float4 a = ((const float4*)(U + (size_t)g * EMB))[lane];
    float4 b = ((const float4*)(I + (size_t)g * EMB))[lane];
    float p = a.x * b.x + a.y * b.y + a.z * b.z + a.w * b.w;
    for (int m = 1; m < 16; m <<= 1) p += __shfl_xor(p, m, 64);
    if (lane == 0) out[g] = p * (1.0f / 16.0f);  // 1/(K+1)^2
}

// ---------------- launch ----------------

static inline char* align16(char* p) {
    return (char*)(((uintptr_t)p + 15) & ~(uintptr_t)15);
}

extern "C" void kernel_launch(void* const* d_in, const int* in_sizes, int n_in,
                              void* d_out, int out_size, void* d_ws, size_t ws_size,
                              hipStream_t stream) {
    const float* E0   = (const float*)d_in[0];
    const int*   erow = (const int*)d_in[2];
    const int*   ecol = (const int*)d_in[3];
    const int*   ub   = (const int*)d_in[4];
    const int*   ib   = (const int*)d_in[5];
    float* pred = (float*)d_out;

    char* p = (char*)d_ws;
    unsigned short* F0  = (unsigned short*)p; p = align16(p + (size_t)N_NODES * EMB * 2);
    unsigned short* Abf = (unsigned short*)p; p = align16(p + (size_t)N_NODES * EMB * 2);
    unsigned short* Bbf = (unsigned short*)p; p = align16(p + (size_t)N_NODES * EMB * 2);
    float* U       = (float*)p;    p = align16(p + (size_t)BATCH * EMB * 4);
    float* I       = (float*)p;    p = align16(p + (size_t)BATCH * EMB * 4);
    int*   bcursor = (int*)p;      p = align16(p + (size_t)NBKT * 4);
    int*   bbase   = (int*)p;      p = align16(p + (size_t)(NBKT + 1) * 4);
    int*   rowptr  = (int*)p;      p = align16(p + (size_t)(N_NODES + 1) * 4);
    float* dinv    = (float*)p;    p = align16(p + (size_t)N_NODES * 4);
    float* s2      = (float*)p;    p = align16(p + (size_t)N_NODES * 4);
    float* srt     = (float*)p;    p = align16(p + (size_t)N_NODES * 4);
    int*   csrc    = (int*)p;      p = align16(p + (size_t)NEDGES * 4);
    unsigned* tmp  = (unsigned*)p; p = align16(p + (size_t)NBKT * BCAP * 4);

    const int BS = 256;
    // CSR build
    k_zero<<<(NBKT + BS - 1) / BS, BS, 0, stream>>>(bcursor);
    k_partC<<<PC_NWG, PC_BS, 0, stream>>>(erow, ecol, bcursor, tmp);
    k_bscan<<<1, 512, 0, stream>>>(bcursor, bbase, rowptr);
    k_rows_place<<<NBKT, 512, 0, stream>>>(tmp, bcursor, bbase, rowptr, dinv, s2, srt, csrc);
    k_cast<<<(N_NODES * EMB / 4 + BS - 1) / BS, BS, 0, stream>>>(E0, dinv, F0);

    k_gather_init<<<(2 * BATCH * 16 + BS - 1) / BS, BS, 0, stream>>>(E0, ub, ib, U, I);

    const int spmm_grid = (N_NODES * 8 + BS - 1) / BS;
    const int acc_grid  = (2 * BATCH * 16 + BS - 1) / BS;

    // hop 1: F0 -> Abf
    k_spmm<<<spmm_grid, BS, 0, stream>>>(F0, Abf, rowptr, csrc, s2);
    k_gather_acc<<<acc_grid, BS, 0, stream>>>(Abf, srt, ub, ib, U, I);
    // hop 2: Abf -> Bbf
    k_spmm<<<spmm_grid, BS, 0, stream>>>(Abf, Bbf, rowptr, csrc, s2);
    k_gather_acc<<<acc_grid, BS, 0, stream>>>(Bbf, srt, ub, ib, U, I);
    // hop 3: Bbf -> Abf
    k_spmm<<<spmm_grid, BS, 0, stream>>>(Bbf, Abf, rowptr, csrc, s2);
    k_gather_acc<<<acc_grid, BS, 0, stream>>>(Abf, srt, ub, ib, U, I);

    // readout
    k_dot<<<(BATCH * 16 + BS - 1) / BS, BS, 0, stream>>>(U, I, pred);
}

// Round 7
// 247.494 us; speedup vs baseline: 6.5162x; 1.1835x over previous
//
#include <hip/hip_runtime.h>

#define N_USERS 100000
#define N_ITEMS 50000
#define N_NODES 150000
#define NEDGES  4000000
#define EMB     64
#define BATCH   16384

#define RSHIFT  9
#define RPB     512                          // rows per bucket
#define NBKT    ((N_NODES + RPB - 1) / RPB)  // 293
#define BCAP    24576                        // max edges/bucket

#define PC_BS   1024
#define PC_CH   16384
#define PC_EPT  (PC_CH / PC_BS)                 // 16 edges/thread
#define PC_NWG  ((NEDGES + PC_CH - 1) / PC_CH)  // 245

// ---------------- helpers ----------------

__device__ __forceinline__ unsigned short f2b(float f) {  // fp32 -> bf16 RNE
    unsigned u = __float_as_uint(f);
    return (unsigned short)((u + 0x7FFFu + ((u >> 16) & 1u)) >> 16);
}
__device__ __forceinline__ float b2f_lo(unsigned v) { return __uint_as_float(v << 16); }
__device__ __forceinline__ float b2f_hi(unsigned v) { return __uint_as_float(v & 0xFFFF0000u); }

__device__ __forceinline__ void acc8(float* a, uint4 v) {
    a[0] += b2f_lo(v.x); a[1] += b2f_hi(v.x);
    a[2] += b2f_lo(v.y); a[3] += b2f_hi(v.y);
    a[4] += b2f_lo(v.z); a[5] += b2f_hi(v.z);
    a[6] += b2f_lo(v.w); a[7] += b2f_hi(v.w);
}

// ---------------- CSR build ----------------

__global__ void k_zero(int* __restrict__ bcursor) {
    int i = blockIdx.x * blockDim.x + threadIdx.x;
    if (i < NBKT) bcursor[i] = 0;
}

// LDS-staged bucket partition; edges cached in registers across the two passes
__global__ __launch_bounds__(PC_BS) void k_partC(const int* __restrict__ erow,
                                                 const int* __restrict__ ecol,
                                                 int* __restrict__ bcursor,
                                                 unsigned* __restrict__ tmp) {
    __shared__ int cnt[NBKT];
    __shared__ int base_[NBKT];
    const int t = threadIdx.x;
    for (int i = t; i < NBKT; i += PC_BS) cnt[i] = 0;
    __syncthreads();
    const int e0 = blockIdx.x * PC_CH;
    int rr[PC_EPT], cc[PC_EPT];
#pragma unroll
    for (int k = 0; k < PC_EPT; ++k) {
        int e = e0 + t + k * PC_BS;
        if (e < NEDGES) {
            rr[k] = erow[e];
            cc[k] = ecol[e];
            atomicAdd(&cnt[rr[k] >> RSHIFT], 1);
        } else rr[k] = -1;
    }
    __syncthreads();
    for (int i = t; i < NBKT; i += PC_BS) {
        base_[i] = cnt[i] ? atomicAdd(&bcursor[i], cnt[i]) : 0;
        cnt[i] = 0;
    }
    __syncthreads();
#pragma unroll
    for (int k = 0; k < PC_EPT; ++k) {
        if (rr[k] >= 0) {
            int b = rr[k] >> RSHIFT;
            int pos = base_[b] + atomicAdd(&cnt[b], 1);
            if (pos < BCAP)
                tmp[(size_t)b * BCAP + pos] =
                    ((unsigned)(rr[k] & (RPB - 1)) << 18) | (unsigned)cc[k];
        }
    }
}

// scan of per-bucket totals
__global__ __launch_bounds__(512) void k_bscan(const int* __restrict__ bcursor,
                                               int* __restrict__ bbase,
                                               int* __restrict__ rowptr) {
    __shared__ int s[512];
    const int t = threadIdx.x;
    int v = 0;
    if (t < NBKT) { v = bcursor[t]; if (v > BCAP) v = BCAP; }
    s[t] = v;
    __syncthreads();
    for (int off = 1; off < 512; off <<= 1) {
        int u = (t >= off) ? s[t - off] : 0;
        __syncthreads();
        s[t] += u;
        __syncthreads();
    }
    if (t < NBKT) bbase[t] = s[t] - v;  // exclusive
    if (t == 511) { bbase[NBKT] = s[511]; rowptr[N_NODES] = s[511]; }
}

// fused: row count (LDS) -> LDS scan -> rowptr + dinv/s2/srt -> place edges
__global__ __launch_bounds__(512) void k_rows_place(const unsigned* __restrict__ tmp,
                                                    const int* __restrict__ bcursor,
                                                    const int* __restrict__ bbase,
                                                    int* __restrict__ rowptr,
                                                    float* __restrict__ dinv,
                                                    float* __restrict__ s2,
                                                    float* __restrict__ srt,
                                                    int* __restrict__ csrc) {
    __shared__ int rc[RPB];
    __shared__ int pre[RPB];
    const int b = blockIdx.x;
    const int t = threadIdx.x;
    rc[t] = 0;
    __syncthreads();
    int n = bcursor[b]; if (n > BCAP) n = BCAP;
    const unsigned* tp = tmp + (size_t)b * BCAP;
    for (int i = t; i < n; i += 512) atomicAdd(&rc[tp[i] >> 18], 1);
    __syncthreads();
    int my = rc[t];
    pre[t] = my;
    __syncthreads();
    for (int off = 1; off < 512; off <<= 1) {
        int u = (t >= off) ? pre[t - off] : 0;
        __syncthreads();
        pre[t] += u;
        __syncthreads();
    }
    int ex   = pre[t] - my;
    int base = bbase[b];
    int r = b * RPB + t;
    if (r < N_NODES) {
        float sr = sqrtf((float)my) + 1e-6f;   // 1/dinv
        float dv = 1.0f / sr;
        rowptr[r] = base + ex;
        dinv[r] = dv;
        s2[r]   = dv * dv;
        srt[r]  = sr;
    }
    __syncthreads();
    rc[t] = base + ex;               // absolute write cursor per row
    __syncthreads();
    for (int i = t; i < n; i += 512) {
        unsigned pk = tp[i];
        int slot = atomicAdd(&rc[pk >> 18], 1);
        csrc[slot] = (int)(pk & 0x3FFFFu);
    }
}

// F0 = dinv * E0, bf16
__global__ void k_cast(const float* __restrict__ E0, const float* __restrict__ dinv,
                       unsigned short* __restrict__ F0) {
    int i = blockIdx.x * blockDim.x + threadIdx.x;  // one float4 per thread
    const int total = N_NODES * EMB / 4;
    if (i >= total) return;
    float dv = dinv[i >> 4];
    float4 v = ((const float4*)E0)[i];
    ushort4 o;
    o.x = f2b(dv * v.x); o.y = f2b(dv * v.y);
    o.z = f2b(dv * v.z); o.w = f2b(dv * v.w);
    ((ushort4*)F0)[i] = o;
}

// ---------------- SpMM core: sum_{c in N(r)} F_in[c], 8 lanes/row ----------

__device__ __forceinline__ void spmm_row(const unsigned short* __restrict__ Fin,
                                         unsigned short* __restrict__ Fout,
                                         const int* __restrict__ cols,
                                         int beg, int end, int g, int lane, float s) {
    float A[8] = {0,0,0,0,0,0,0,0};
    float B[8] = {0,0,0,0,0,0,0,0};
    int j = beg;
    int nscal = (4 - (j & 3)) & 3;   // align to int4
    for (int k = 0; k < nscal && j < end; ++k, ++j) {
        uint4 v = ((const uint4*)(Fin + (size_t)cols[j] * EMB))[lane];
        acc8(A, v);
    }
    for (; j + 8 <= end; j += 8) {
        int4 c0 = *(const int4*)(cols + j);
        int4 c1 = *(const int4*)(cols + j + 4);
        uint4 v0 = ((const uint4*)(Fin + (size_t)c0.x * EMB))[lane];
        uint4 v1 = ((const uint4*)(Fin + (size_t)c0.y * EMB))[lane];
        uint4 v2 = ((const uint4*)(Fin + (size_t)c0.z * EMB))[lane];
        uint4 v3 = ((const uint4*)(Fin + (size_t)c0.w * EMB))[lane];
        uint4 v4 = ((const uint4*)(Fin + (size_t)c1.x * EMB))[lane];
        uint4 v5 = ((const uint4*)(Fin + (size_t)c1.y * EMB))[lane];
        uint4 v6 = ((const uint4*)(Fin + (size_t)c1.z * EMB))[lane];
        uint4 v7 = ((const uint4*)(Fin + (size_t)c1.w * EMB))[lane];
        acc8(A, v0); acc8(B, v1); acc8(A, v2); acc8(B, v3);
        acc8(A, v4); acc8(B, v5); acc8(A, v6); acc8(B, v7);
    }
    for (; j + 4 <= end; j += 4) {
        int4 c = *(const int4*)(cols + j);
        uint4 v0 = ((const uint4*)(Fin + (size_t)c.x * EMB))[lane];
        uint4 v1 = ((const uint4*)(Fin + (size_t)c.y * EMB))[lane];
        uint4 v2 = ((const uint4*)(Fin + (size_t)c.z * EMB))[lane];
        uint4 v3 = ((const uint4*)(Fin + (size_t)c.w * EMB))[lane];
        acc8(A, v0); acc8(B, v1); acc8(A, v2); acc8(B, v3);
    }
    for (; j < end; ++j) {
        uint4 v = ((const uint4*)(Fin + (size_t)cols[j] * EMB))[lane];
        acc8(A, v);
    }
    unsigned o0 = ((unsigned)f2b(s * (A[1] + B[1])) << 16) | f2b(s * (A[0] + B[0]));
    unsigned o1 = ((unsigned)f2b(s * (A[3] + B[3])) << 16) | f2b(s * (A[2] + B[2]));
    unsigned o2 = ((unsigned)f2b(s * (A[5] + B[5])) << 16) | f2b(s * (A[4] + B[4]));
    unsigned o3 = ((unsigned)f2b(s * (A[7] + B[7])) << 16) | f2b(s * (A[6] + B[6]));
    ((uint4*)(Fout + (size_t)g * EMB))[lane] = make_uint4(o0, o1, o2, o3);
}

// dense hop: all rows
__global__ __launch_bounds__(256) void k_spmm(const unsigned short* __restrict__ Fin,
                                              unsigned short* __restrict__ Fout,
                                              const int* __restrict__ rowptr,
                                              const int* __restrict__ cols,
                                              const float* __restrict__ s2) {
    int g    = (blockIdx.x * blockDim.x + threadIdx.x) >> 3;
    int lane = threadIdx.x & 7;
    if (g >= N_NODES) return;
    spmm_row(Fin, Fout, cols, rowptr[g], rowptr[g + 1], g, lane, s2[g]);
}

// sparse hop 3: only batch rows (duplicates write identical values - benign)
__global__ __launch_bounds__(256) void k_spmm3(const unsigned short* __restrict__ Fin,
                                               unsigned short* __restrict__ Fout,
                                               const int* __restrict__ rowptr,
                                               const int* __restrict__ cols,
                                               const float* __restrict__ s2,
                                               const int* __restrict__ ub,
                                               const int* __restrict__ ib) {
    int gi   = (blockIdx.x * blockDim.x + threadIdx.x) >> 3;
    int lane = threadIdx.x & 7;
    if (gi >= 2 * BATCH) return;
    int g = (gi < BATCH) ? ub[gi] : (N_USERS + ib[gi - BATCH]);
    spmm_row(Fin, Fout, cols, rowptr[g], rowptr[g + 1], g, lane, s2[g]);
}

// ---------------- batch-row gather ----------------

__global__ void k_gather_init(const float* __restrict__ E0, const int* __restrict__ ub,
                              const int* __restrict__ ib, float* __restrict__ U,
                              float* __restrict__ I) {
    int g    = (blockIdx.x * blockDim.x + threadIdx.x) >> 4;
    int lane = threadIdx.x & 15;
    if (g >= 2 * BATCH) return;
    if (g < BATCH) {
        int r = ub[g];
        ((float4*)(U + (size_t)g * EMB))[lane] =
            ((const float4*)(E0 + (size_t)r * EMB))[lane];
    } else {
        int bq = g - BATCH;
        int r = N_USERS + ib[bq];
        ((float4*)(I + (size_t)bq * EMB))[lane] =
            ((const float4*)(E0 + (size_t)r * EMB))[lane];
    }
}

// U/I += F[r] * srt[r]   (recovers E_i[r] = F_i[r]/dinv[r])
__global__ void k_gather_acc(const unsigned short* __restrict__ F,
                             const float* __restrict__ srt,
                             const int* __restrict__ ub, const int* __restrict__ ib,
                             float* __restrict__ U, float* __restrict__ I) {
    int g    = (blockIdx.x * blockDim.x + threadIdx.x) >> 4;
    int lane = threadIdx.x & 15;
    if (g >= 2 * BATCH) return;
    int r, bq;
    float* dstbuf;
    if (g < BATCH) { r = ub[g]; bq = g; dstbuf = U; }
    else { bq = g - BATCH; r = N_USERS + ib[bq]; dstbuf = I; }
    float sr = srt[r];
    uint2 v = ((const uint2*)(F + (size_t)r * EMB))[lane];
    float4* dst = (float4*)(dstbuf + (size_t)bq * EMB) + lane;
    float4 a = *dst;
    a.x = fmaf(sr, b2f_lo(v.x), a.x); a.y = fmaf(sr, b2f_hi(v.x), a.y);
    a.z = fmaf(sr, b2f_lo(v.y), a.z); a.w = fmaf(sr, b2f_hi(v.y), a.w);
    *dst = a;
}

// ---------------- fused hop-3 accumulate + dot ----------------

__global__ void k_finish(const unsigned short* __restrict__ F3,
                         const float* __restrict__ srt,
                         const int* __restrict__ ub, const int* __restrict__ ib,
                         const float* __restrict__ U, const float* __restrict__ I,
                         float* __restrict__ out) {
    int q    = (blockIdx.x * blockDim.x + threadIdx.x) >> 4;
    int lane = threadIdx.x & 15;
    if (q >= BATCH) return;
    int u  = ub[q];
    int iv = N_USERS + ib[q];
    float su = srt[u], si = srt[iv];
    float4 a = ((const float4*)(U + (size_t)q * EMB))[lane];
    float4 b = ((const float4*)(I + (size_t)q * EMB))[lane];
    uint2 vu = ((const uint2*)(F3 + (size_t)u * EMB))[lane];
    uint2 vi = ((const uint2*)(F3 + (size_t)iv * EMB))[lane];
    a.x = fmaf(su, b2f_lo(vu.x), a.x); a.y = fmaf(su, b2f_hi(vu.x), a.y);
    a.z = fmaf(su, b2f_lo(vu.y), a.z); a.w = fmaf(su, b2f_hi(vu.y), a.w);
    b.x = fmaf(si, b2f_lo(vi.x), b.x); b.y = fmaf(si, b2f_hi(vi.x), b.y);
    b.z = fmaf(si, b2f_lo(vi.y), b.z); b.w = fmaf(si, b2f_hi(vi.y), b.w);
    float p = a.x * b.x + a.y * b.y + a.z * b.z + a.w * b.w;
    for (int m = 1; m < 16; m <<= 1) p += __shfl_xor(p, m, 64);
    if (lane == 0) out[q] = p * (1.0f / 16.0f);  // 1/(K+1)^2
}

// ---------------- launch ----------------

static inline char* align16(char* p) {
    return (char*)(((uintptr_t)p + 15) & ~(uintptr_t)15);
}

extern "C" void kernel_launch(void* const* d_in, const int* in_sizes, int n_in,
                              void* d_out, int out_size, void* d_ws, size_t ws_size,
                              hipStream_t stream) {
    const float* E0   = (const float*)d_in[0];
    const int*   erow = (const int*)d_in[2];
    const int*   ecol = (const int*)d_in[3];
    const int*   ub   = (const int*)d_in[4];
    const int*   ib   = (const int*)d_in[5];
    float* pred = (float*)d_out;

    char* p = (char*)d_ws;
    unsigned short* F0  = (unsigned short*)p; p = align16(p + (size_t)N_NODES * EMB * 2);
    unsigned short* Abf = (unsigned short*)p; p = align16(p + (size_t)N_NODES * EMB * 2);
    unsigned short* Bbf = (unsigned short*)p; p = align16(p + (size_t)N_NODES * EMB * 2);
    float* U       = (float*)p;    p = align16(p + (size_t)BATCH * EMB * 4);
    float* I       = (float*)p;    p = align16(p + (size_t)BATCH * EMB * 4);
    int*   bcursor = (int*)p;      p = align16(p + (size_t)NBKT * 4);
    int*   bbase   = (int*)p;      p = align16(p + (size_t)(NBKT + 1) * 4);
    int*   rowptr  = (int*)p;      p = align16(p + (size_t)(N_NODES + 1) * 4);
    float* dinv    = (float*)p;    p = align16(p + (size_t)N_NODES * 4);
    float* s2      = (float*)p;    p = align16(p + (size_t)N_NODES * 4);
    float* srt     = (float*)p;    p = align16(p + (size_t)N_NODES * 4);
    int*   csrc    = (int*)p;      p = align16(p + (size_t)NEDGES * 4);
    unsigned* tmp  = (unsigned*)p; p = align16(p + (size_t)NBKT * BCAP * 4);

    const int BS = 256;
    // CSR build
    k_zero<<<(NBKT + BS - 1) / BS, BS, 0, stream>>>(bcursor);
    k_partC<<<PC_NWG, PC_BS, 0, stream>>>(erow, ecol, bcursor, tmp);
    k_bscan<<<1, 512, 0, stream>>>(bcursor, bbase, rowptr);
    k_rows_place<<<NBKT, 512, 0, stream>>>(tmp, bcursor, bbase, rowptr, dinv, s2, srt, csrc);
    k_cast<<<(N_NODES * EMB / 4 + BS - 1) / BS, BS, 0, stream>>>(E0, dinv, F0);

    k_gather_init<<<(2 * BATCH * 16 + BS - 1) / BS, BS, 0, stream>>>(E0, ub, ib, U, I);

    const int spmm_grid = (N_NODES * 8 + BS - 1) / BS;
    const int acc_grid  = (2 * BATCH * 16 + BS - 1) / BS;

    // hop 1: F0 -> Abf (dense)
    k_spmm<<<spmm_grid, BS, 0, stream>>>(F0, Abf, rowptr, csrc, s2);
    k_gather_acc<<<acc_grid, BS, 0, stream>>>(Abf, srt, ub, ib, U, I);
    // hop 2: Abf -> Bbf (dense)
    k_spmm<<<spmm_grid, BS, 0, stream>>>(Abf, Bbf, rowptr, csrc, s2);
    k_gather_acc<<<acc_grid, BS, 0, stream>>>(Bbf, srt, ub, ib, U, I);
    // hop 3: Bbf -> Abf, batch rows only
    k_spmm3<<<(2 * BATCH * 8 + BS - 1) / BS, BS, 0, stream>>>(Bbf, Abf, rowptr, csrc,
                                                              s2, ub, ib);
    // fused hop-3 accumulate + dot
    k_finish<<<(BATCH * 16 + BS - 1) / BS, BS, 0, stream>>>(Abf, srt, ub, ib, U, I, pred);
}